// Round 1
// baseline (1468.765 us; speedup 1.0000x reference)
//
#include <hip/hip_runtime.h>

#define N_NODES 10000
#define N_RELS  50
#define R_AUG   101
#define D       128
#define N_EDGES 320000
#define E_AUG   650000   /* 2*N_EDGES + N_NODES */
#define N_BATCH 65536

typedef short bf16x8 __attribute__((ext_vector_type(8)));
typedef float f32x4  __attribute__((ext_vector_type(4)));

__device__ __forceinline__ unsigned short f2bf(float f) {
    union { float f; unsigned int u; } v; v.f = f;
    unsigned int r = (v.u + 0x7FFFu + ((v.u >> 16) & 1u)) >> 16;
    return (unsigned short)r;
}
__device__ __forceinline__ float bf2f(unsigned short h) {
    union { unsigned int u; float f; } v; v.u = ((unsigned int)h) << 16;
    return v.f;
}

__device__ __forceinline__ void decode_edge(const int* __restrict__ g, int e,
                                            int& src, int& rel, int& dst) {
    if (e < N_EDGES)            { src = g[3*e];     rel = g[3*e+1];          dst = g[3*e+2]; }
    else if (e < 2*N_EDGES)     { int b = e - N_EDGES;
                                  src = g[3*b+2];   rel = g[3*b+1] + N_RELS; dst = g[3*b];   }
    else                        { int n = e - 2*N_EDGES; src = n; dst = n; rel = 2*N_RELS;   }
}

// ---------------- small prep kernels ----------------

__global__ __launch_bounds__(256) void convert_x(const float* __restrict__ x,
                                                 unsigned short* __restrict__ xb) {
    int i = blockIdx.x * 256 + threadIdx.x;   // grid covers N_NODES*D exactly
    xb[i] = f2bf(x[i]);
}

__global__ __launch_bounds__(256) void init_h(float* __restrict__ h1, float* __restrict__ h2,
                                              const float* __restrict__ b1,
                                              const float* __restrict__ b2) {
    int i = blockIdx.x * 256 + threadIdx.x;
    int d = i & (D - 1);
    h1[i] = b1[d];
    h2[i] = b2[d];
}

// W (r,d,o) fp32  ->  Wt (r,o,d) bf16, both weight tensors in one grid
__global__ __launch_bounds__(256) void transpose_w(const float* __restrict__ W1,
                                                   const float* __restrict__ W2,
                                                   unsigned short* __restrict__ W1t,
                                                   unsigned short* __restrict__ W2t) {
    __shared__ float tile[64][65];
    int z = blockIdx.z;
    const float* W = (z < R_AUG) ? W1 : W2;
    unsigned short* Wt = (z < R_AUG) ? W1t : W2t;
    int r = (z < R_AUG) ? z : (z - R_AUG);
    int d0 = blockIdx.x * 64, o0 = blockIdx.y * 64;
    int tx = threadIdx.x & 63, ty = threadIdx.x >> 6;
    #pragma unroll
    for (int i = ty; i < 64; i += 4)
        tile[i][tx] = W[((size_t)r * D + (d0 + i)) * D + (o0 + tx)];
    __syncthreads();
    #pragma unroll
    for (int i = ty; i < 64; i += 4)
        Wt[((size_t)r * D + (o0 + i)) * D + (d0 + tx)] = f2bf(tile[tx][i]);
}

__global__ __launch_bounds__(256) void deg_kernel(const int* __restrict__ g,
                                                  float* __restrict__ deg) {
    int e = blockIdx.x * 256 + threadIdx.x;
    if (e >= E_AUG) return;
    int src, rel, dst;
    decode_edge(g, e, src, rel, dst);
    atomicAdd(&deg[rel * N_NODES + dst], 1.0f);
}

__global__ __launch_bounds__(256) void inv_kernel(float* __restrict__ norm) {
    int i = blockIdx.x * 256 + threadIdx.x;
    if (i >= R_AUG * N_NODES) return;
    norm[i] = 1.0f / fmaxf(norm[i], 1.0f);
}

__global__ __launch_bounds__(256) void relu_conv(const float* __restrict__ h,
                                                 unsigned short* __restrict__ hb) {
    int i = blockIdx.x * 256 + threadIdx.x;
    hb[i] = f2bf(fmaxf(h[i], 0.0f));
}

// ---------------- batched GEMM: Z[rc][m][o] = Xb[m][:] @ W[r][:][o] (bf16 in, bf16 out) ----------------
// grid: (79 M-tiles, Rc relations), block 256 (4 waves, each 64x64 of the 128x128 tile)

__global__ __launch_bounds__(256) void gemm_chunk(const unsigned short* __restrict__ xb,
                                                  const unsigned short* __restrict__ Wt,
                                                  unsigned short* __restrict__ Z,
                                                  int r0) {
    __shared__ unsigned short Bs[128][136];   // Wt[r] rows: [o][k], +8 pad (2-way free aliasing)
    int mt = blockIdx.x;
    int rc = blockIdx.y;
    int r  = r0 + rc;
    int t  = threadIdx.x;

    // stage Wt[r] (128 x 128 bf16): 256 threads x 8 chunks of 16B
    #pragma unroll
    for (int i = 0; i < 8; i++) {
        int c = t + 256 * i;
        int row = c >> 4, col = (c & 15) * 8;
        *(uint4*)&Bs[row][col] = *(const uint4*)(Wt + ((size_t)r * D + row) * D + col);
    }
    __syncthreads();

    int wave = t >> 6, lane = t & 63;
    int mo = (wave >> 1) * 64, no = (wave & 1) * 64;
    int lr = lane & 15;        // row within 16x16 frag
    int lq = lane >> 4;        // quad

    int m0 = mt * 128;
    f32x4 acc[4][4] = {};

    #pragma unroll
    for (int ks = 0; ks < 4; ks++) {
        int kbase = ks * 32 + lq * 8;
        bf16x8 a[4], b[4];
        #pragma unroll
        for (int i = 0; i < 4; i++) {
            int m = m0 + mo + i * 16 + lr;
            bf16x8 zv = {};
            a[i] = (m < N_NODES) ? *(const bf16x8*)(xb + (size_t)m * D + kbase) : zv;
            b[i] = *(const bf16x8*)(&Bs[no + i * 16 + lr][kbase]);
        }
        #pragma unroll
        for (int i = 0; i < 4; i++)
            #pragma unroll
            for (int j = 0; j < 4; j++)
                acc[i][j] = __builtin_amdgcn_mfma_f32_16x16x32_bf16(a[i], b[j], acc[i][j], 0, 0, 0);
    }

    // C layout: col = lane&15, row = (lane>>4)*4 + reg
    #pragma unroll
    for (int i = 0; i < 4; i++) {
        #pragma unroll
        for (int j = 0; j < 4; j++) {
            int col = no + j * 16 + lr;
            #pragma unroll
            for (int rg = 0; rg < 4; rg++) {
                int m = m0 + mo + i * 16 + lq * 4 + rg;
                if (m < N_NODES)
                    Z[((size_t)rc * N_NODES + m) * D + col] = f2bf(acc[i][j][rg]);
            }
        }
    }
}

// ---------------- edge pass: h[dst] += norm[rel,dst] * Z[rel-r0][src]  (one wave per edge) ----------------

__global__ __launch_bounds__(256) void edge_pass(const int* __restrict__ g,
                                                 const float* __restrict__ norm,
                                                 const unsigned short* __restrict__ Z,
                                                 float* __restrict__ h,
                                                 int r0, int r1) {
    int e = blockIdx.x * 4 + (threadIdx.x >> 6);
    if (e >= E_AUG) return;
    int lane = threadIdx.x & 63;
    int src, rel, dst;
    decode_edge(g, e, src, rel, dst);
    if (rel < r0 || rel >= r1) return;
    float nrm = norm[rel * N_NODES + dst];
    const unsigned short* zp = Z + (((size_t)(rel - r0) * N_NODES + src) << 7) + 2 * lane;
    unsigned int packed = *(const unsigned int*)zp;
    float v0 = bf2f((unsigned short)(packed & 0xFFFF)) * nrm;
    float v1 = bf2f((unsigned short)(packed >> 16)) * nrm;
    float* hp = h + (size_t)dst * D + 2 * lane;
    atomicAdd(hp, v0);
    atomicAdd(hp + 1, v1);
}

// ---------------- scoring: out[i] = sum_d h2[s][d]*rel[p][d]*h2[o][d] (one wave per item) ----------------

__global__ __launch_bounds__(256) void score_kernel(const int* __restrict__ batch,
                                                    const float* __restrict__ h2,
                                                    const float* __restrict__ rels,
                                                    float* __restrict__ out) {
    int i = blockIdx.x * 4 + (threadIdx.x >> 6);
    if (i >= N_BATCH) return;
    int lane = threadIdx.x & 63;
    int bs = batch[3*i], bp = batch[3*i+1], bo = batch[3*i+2];
    float2 s = *(const float2*)(h2   + (size_t)bs * D + lane * 2);
    float2 p = *(const float2*)(rels + (size_t)bp * D + lane * 2);
    float2 o = *(const float2*)(h2   + (size_t)bo * D + lane * 2);
    float v = s.x * p.x * o.x + s.y * p.y * o.y;
    #pragma unroll
    for (int off = 32; off > 0; off >>= 1) v += __shfl_down(v, off, 64);
    if (lane == 0) out[i] = v;
}

// ---------------- host ----------------

extern "C" void kernel_launch(void* const* d_in, const int* in_sizes, int n_in,
                              void* d_out, int out_size, void* d_ws, size_t ws_size,
                              hipStream_t stream) {
    const int*   graph = (const int*)  d_in[0];
    const int*   batch = (const int*)  d_in[1];
    const float* emb   = (const float*)d_in[2];
    const float* W1    = (const float*)d_in[3];
    const float* b1    = (const float*)d_in[4];
    const float* W2    = (const float*)d_in[5];
    const float* b2    = (const float*)d_in[6];
    const float* rels  = (const float*)d_in[7];
    float* out = (float*)d_out;

    char* base = (char*)d_ws;
    size_t off = 0;
    auto take = [&](size_t bytes) -> char* {
        char* q = base + off;
        off += (bytes + 255) & ~(size_t)255;
        return q;
    };
    float*          norm = (float*)         take((size_t)R_AUG * N_NODES * 4);
    unsigned short* xb   = (unsigned short*)take((size_t)N_NODES * D * 2);
    float*          h1   = (float*)         take((size_t)N_NODES * D * 4);
    float*          h2   = (float*)         take((size_t)N_NODES * D * 4);
    unsigned short* h1b  = (unsigned short*)take((size_t)N_NODES * D * 2);
    unsigned short* W1t  = (unsigned short*)take((size_t)R_AUG * D * D * 2);
    unsigned short* W2t  = (unsigned short*)take((size_t)R_AUG * D * D * 2);
    size_t zslice = (size_t)N_NODES * D * 2;   // bytes per relation slice of Z
    size_t zavail = (ws_size > off) ? (ws_size - off) : 0;
    int Rc = (int)(zavail / zslice);
    if (Rc > R_AUG) Rc = R_AUG;
    if (Rc < 1) Rc = 1;   // requires ws_size >= ~29 MB
    unsigned short* Z = (unsigned short*)(base + off);

    hipMemsetAsync(norm, 0, (size_t)R_AUG * N_NODES * 4, stream);
    convert_x<<<dim3((N_NODES * D) / 256), 256, 0, stream>>>(emb, xb);
    init_h<<<dim3((N_NODES * D) / 256), 256, 0, stream>>>(h1, h2, b1, b2);
    transpose_w<<<dim3(2, 2, 2 * R_AUG), 256, 0, stream>>>(W1, W2, W1t, W2t);
    deg_kernel<<<dim3((E_AUG + 255) / 256), 256, 0, stream>>>(graph, norm);
    inv_kernel<<<dim3((R_AUG * N_NODES + 255) / 256), 256, 0, stream>>>(norm);

    const int nmt = (N_NODES + 127) / 128;  // 79
    for (int r0 = 0; r0 < R_AUG; r0 += Rc) {
        int rn = R_AUG - r0 < Rc ? R_AUG - r0 : Rc;
        gemm_chunk<<<dim3(nmt, rn), 256, 0, stream>>>(xb, W1t, Z, r0);
        edge_pass<<<dim3((E_AUG + 3) / 4), 256, 0, stream>>>(graph, norm, Z, h1, r0, r0 + rn);
    }
    relu_conv<<<dim3((N_NODES * D) / 256), 256, 0, stream>>>(h1, h1b);
    for (int r0 = 0; r0 < R_AUG; r0 += Rc) {
        int rn = R_AUG - r0 < Rc ? R_AUG - r0 : Rc;
        gemm_chunk<<<dim3(nmt, rn), 256, 0, stream>>>(h1b, W2t, Z, r0);
        edge_pass<<<dim3((E_AUG + 3) / 4), 256, 0, stream>>>(graph, norm, Z, h2, r0, r0 + rn);
    }
    score_kernel<<<dim3(N_BATCH / 4), 256, 0, stream>>>(batch, h2, rels, out);
}

// Round 2
// 635.323 us; speedup vs baseline: 2.3118x; 2.3118x over previous
//
#include <hip/hip_runtime.h>

#define N_NODES 10000
#define N_RELS  50
#define R_AUG   101
#define D       128
#define N_EDGES 320000
#define E_AUG   650000   /* 2*N_EDGES + N_NODES */
#define N_BATCH 65536

typedef short bf16x8 __attribute__((ext_vector_type(8)));
typedef float f32x4  __attribute__((ext_vector_type(4)));

__device__ __forceinline__ unsigned short f2bf(float f) {
    union { float f; unsigned int u; } v; v.f = f;
    unsigned int r = (v.u + 0x7FFFu + ((v.u >> 16) & 1u)) >> 16;
    return (unsigned short)r;
}
__device__ __forceinline__ float bf2f(unsigned short h) {
    union { unsigned int u; float f; } v; v.u = ((unsigned int)h) << 16;
    return v.f;
}
__device__ __forceinline__ float u2f(unsigned int u) {
    union { unsigned int u; float f; } v; v.u = u; return v.f;
}
__device__ __forceinline__ unsigned int f2u(float f) {
    union { float f; unsigned int u; } v; v.f = f; return v.u;
}

__device__ __forceinline__ void decode_edge(const int* __restrict__ g, int e,
                                            int& src, int& rel, int& dst) {
    if (e < N_EDGES)            { src = g[3*e];     rel = g[3*e+1];          dst = g[3*e+2]; }
    else if (e < 2*N_EDGES)     { int b = e - N_EDGES;
                                  src = g[3*b+2];   rel = g[3*b+1] + N_RELS; dst = g[3*b];   }
    else                        { int n = e - 2*N_EDGES; src = n; dst = n; rel = 2*N_RELS;   }
}

// ---------------- small prep kernels ----------------

__global__ __launch_bounds__(256) void convert_x(const float* __restrict__ x,
                                                 unsigned short* __restrict__ xb) {
    int i = blockIdx.x * 256 + threadIdx.x;   // grid covers N_NODES*D exactly
    xb[i] = f2bf(x[i]);
}

__global__ __launch_bounds__(256) void init_h(float* __restrict__ h1, float* __restrict__ h2,
                                              const float* __restrict__ b1,
                                              const float* __restrict__ b2) {
    int i = blockIdx.x * 256 + threadIdx.x;
    int d = i & (D - 1);
    h1[i] = b1[d];
    h2[i] = b2[d];
}

// W (r,d,o) fp32  ->  Wt (r,o,d) bf16, both weight tensors in one grid
__global__ __launch_bounds__(256) void transpose_w(const float* __restrict__ W1,
                                                   const float* __restrict__ W2,
                                                   unsigned short* __restrict__ W1t,
                                                   unsigned short* __restrict__ W2t) {
    __shared__ float tile[64][65];
    int z = blockIdx.z;
    const float* W = (z < R_AUG) ? W1 : W2;
    unsigned short* Wt = (z < R_AUG) ? W1t : W2t;
    int r = (z < R_AUG) ? z : (z - R_AUG);
    int d0 = blockIdx.x * 64, o0 = blockIdx.y * 64;
    int tx = threadIdx.x & 63, ty = threadIdx.x >> 6;
    #pragma unroll
    for (int i = ty; i < 64; i += 4)
        tile[i][tx] = W[((size_t)r * D + (d0 + i)) * D + (o0 + tx)];
    __syncthreads();
    #pragma unroll
    for (int i = ty; i < 64; i += 4)
        Wt[((size_t)r * D + (o0 + i)) * D + (d0 + tx)] = f2bf(tile[tx][i]);
}

// degree histogram per (rel,dst) AND per dst
__global__ __launch_bounds__(256) void deg_hist(const int* __restrict__ g,
                                                float* __restrict__ deg,
                                                int* __restrict__ cnt) {
    int e = blockIdx.x * 256 + threadIdx.x;
    if (e >= E_AUG) return;
    int src, rel, dst;
    decode_edge(g, e, src, rel, dst);
    atomicAdd(&deg[rel * N_NODES + dst], 1.0f);
    atomicAdd(&cnt[dst], 1);
}

__global__ __launch_bounds__(256) void inv_kernel(float* __restrict__ norm) {
    int i = blockIdx.x * 256 + threadIdx.x;
    if (i >= R_AUG * N_NODES) return;
    norm[i] = 1.0f / fmaxf(norm[i], 1.0f);
}

// single-block exclusive scan over cnt[N_NODES] -> offs[N_NODES+1], cursor copy
__global__ __launch_bounds__(256) void scan_kernel(const int* __restrict__ cnt,
                                                   int* __restrict__ offs,
                                                   int* __restrict__ cursor) {
    __shared__ int wsum[4];
    int t = threadIdx.x, lane = t & 63, w = t >> 6;
    int carry = 0;
    for (int base = 0; base < N_NODES; base += 256) {
        int i = base + t;
        int v = (i < N_NODES) ? cnt[i] : 0;
        int incl = v;
        #pragma unroll
        for (int off = 1; off < 64; off <<= 1) {
            int u = __shfl_up(incl, off, 64);
            if (lane >= off) incl += u;
        }
        if (lane == 63) wsum[w] = incl;
        __syncthreads();
        int woff = 0;
        for (int k = 0; k < w; k++) woff += wsum[k];
        int excl = carry + woff + incl - v;
        if (i < N_NODES) { offs[i] = excl; cursor[i] = excl; }
        carry += wsum[0] + wsum[1] + wsum[2] + wsum[3];
        __syncthreads();
    }
    if (t == 0) offs[N_NODES] = carry;
}

// scatter edges into dst-sorted order; record = (rel<<16 | src, norm bits)
__global__ __launch_bounds__(256) void scatter_kernel(const int* __restrict__ g,
                                                      const float* __restrict__ norm,
                                                      int* __restrict__ cursor,
                                                      uint2* __restrict__ sorted) {
    int e = blockIdx.x * 256 + threadIdx.x;
    if (e >= E_AUG) return;
    int src, rel, dst;
    decode_edge(g, e, src, rel, dst);
    int pos = atomicAdd(&cursor[dst], 1);
    uint2 rec;
    rec.x = ((unsigned)rel << 16) | (unsigned)src;
    rec.y = f2u(norm[rel * N_NODES + dst]);
    sorted[pos] = rec;
}

__global__ __launch_bounds__(256) void relu_conv(const float* __restrict__ h,
                                                 unsigned short* __restrict__ hb) {
    int i = blockIdx.x * 256 + threadIdx.x;
    hb[i] = f2bf(fmaxf(h[i], 0.0f));
}

// ---------------- batched GEMM: Z[rc][m][o] = Xb[m][:] @ W[r][:][o] (bf16 in, bf16 out) ----------------

__global__ __launch_bounds__(256) void gemm_chunk(const unsigned short* __restrict__ xb,
                                                  const unsigned short* __restrict__ Wt,
                                                  unsigned short* __restrict__ Z,
                                                  int r0) {
    __shared__ unsigned short Bs[128][136];   // Wt[r] rows: [o][k], +8 pad
    int mt = blockIdx.x;
    int rc = blockIdx.y;
    int r  = r0 + rc;
    int t  = threadIdx.x;

    #pragma unroll
    for (int i = 0; i < 8; i++) {
        int c = t + 256 * i;
        int row = c >> 4, col = (c & 15) * 8;
        *(uint4*)&Bs[row][col] = *(const uint4*)(Wt + ((size_t)r * D + row) * D + col);
    }
    __syncthreads();

    int wave = t >> 6, lane = t & 63;
    int mo = (wave >> 1) * 64, no = (wave & 1) * 64;
    int lr = lane & 15;
    int lq = lane >> 4;

    int m0 = mt * 128;
    f32x4 acc[4][4] = {};

    #pragma unroll
    for (int ks = 0; ks < 4; ks++) {
        int kbase = ks * 32 + lq * 8;
        bf16x8 a[4], b[4];
        #pragma unroll
        for (int i = 0; i < 4; i++) {
            int m = m0 + mo + i * 16 + lr;
            bf16x8 zv = {};
            a[i] = (m < N_NODES) ? *(const bf16x8*)(xb + (size_t)m * D + kbase) : zv;
            b[i] = *(const bf16x8*)(&Bs[no + i * 16 + lr][kbase]);
        }
        #pragma unroll
        for (int i = 0; i < 4; i++)
            #pragma unroll
            for (int j = 0; j < 4; j++)
                acc[i][j] = __builtin_amdgcn_mfma_f32_16x16x32_bf16(a[i], b[j], acc[i][j], 0, 0, 0);
    }

    #pragma unroll
    for (int i = 0; i < 4; i++) {
        #pragma unroll
        for (int j = 0; j < 4; j++) {
            int col = no + j * 16 + lr;
            #pragma unroll
            for (int rg = 0; rg < 4; rg++) {
                int m = m0 + mo + i * 16 + lq * 4 + rg;
                if (m < N_NODES)
                    Z[((size_t)rc * N_NODES + m) * D + col] = f2bf(acc[i][j][rg]);
            }
        }
    }
}

// ---------------- aggregation: one wave per dst, no atomics ----------------
// h[dst] += sum over edges of norm * Z[rel-r0][src]  (fp32 accumulate in regs)

__global__ __launch_bounds__(256) void agg_pass(const uint2* __restrict__ sorted,
                                                const int* __restrict__ offs,
                                                const unsigned short* __restrict__ Z,
                                                float* __restrict__ h,
                                                int r0, int r1) {
    int w = threadIdx.x >> 6, lane = threadIdx.x & 63;
    int dst = blockIdx.x * 4 + w;
    if (dst >= N_NODES) return;
    int e0 = offs[dst], e1 = offs[dst + 1];
    float ax = 0.0f, ay = 0.0f;

    for (int base = e0; base < e1; base += 64) {
        int n = e1 - base; if (n > 64) n = 64;
        uint2 rec = {0u, 0u};
        if (lane < n) rec = sorted[base + lane];
        #pragma unroll 4
        for (int j = 0; j < n; j++) {
            unsigned p  = (unsigned)__shfl((int)rec.x, j, 64);
            unsigned nb = (unsigned)__shfl((int)rec.y, j, 64);
            int rel = (int)(p >> 16), src = (int)(p & 0xFFFFu);
            if (rel >= r0 && rel < r1) {
                float nrm = u2f(nb);
                unsigned z = *(const unsigned int*)(Z + (((size_t)(rel - r0) * N_NODES + src) << 7) + 2 * lane);
                ax += nrm * bf2f((unsigned short)(z & 0xFFFFu));
                ay += nrm * bf2f((unsigned short)(z >> 16));
            }
        }
    }
    float* hp = h + ((size_t)dst << 7) + 2 * lane;
    hp[0] += ax;
    hp[1] += ay;
}

// ---------------- scoring ----------------

__global__ __launch_bounds__(256) void score_kernel(const int* __restrict__ batch,
                                                    const float* __restrict__ h2,
                                                    const float* __restrict__ rels,
                                                    float* __restrict__ out) {
    int i = blockIdx.x * 4 + (threadIdx.x >> 6);
    if (i >= N_BATCH) return;
    int lane = threadIdx.x & 63;
    int bs = batch[3*i], bp = batch[3*i+1], bo = batch[3*i+2];
    float2 s = *(const float2*)(h2   + (size_t)bs * D + lane * 2);
    float2 p = *(const float2*)(rels + (size_t)bp * D + lane * 2);
    float2 o = *(const float2*)(h2   + (size_t)bo * D + lane * 2);
    float v = s.x * p.x * o.x + s.y * p.y * o.y;
    #pragma unroll
    for (int off = 32; off > 0; off >>= 1) v += __shfl_down(v, off, 64);
    if (lane == 0) out[i] = v;
}

// ---------------- host ----------------

extern "C" void kernel_launch(void* const* d_in, const int* in_sizes, int n_in,
                              void* d_out, int out_size, void* d_ws, size_t ws_size,
                              hipStream_t stream) {
    const int*   graph = (const int*)  d_in[0];
    const int*   batch = (const int*)  d_in[1];
    const float* emb   = (const float*)d_in[2];
    const float* W1    = (const float*)d_in[3];
    const float* b1    = (const float*)d_in[4];
    const float* W2    = (const float*)d_in[5];
    const float* b2    = (const float*)d_in[6];
    const float* rels  = (const float*)d_in[7];
    float* out = (float*)d_out;

    char* base = (char*)d_ws;
    size_t off = 0;
    auto take = [&](size_t bytes) -> char* {
        char* q = base + off;
        off += (bytes + 255) & ~(size_t)255;
        return q;
    };
    float*          norm   = (float*)         take((size_t)R_AUG * N_NODES * 4);
    unsigned short* xb     = (unsigned short*)take((size_t)N_NODES * D * 2);
    float*          h1     = (float*)         take((size_t)N_NODES * D * 4);
    float*          h2     = (float*)         take((size_t)N_NODES * D * 4);
    unsigned short* h1b    = (unsigned short*)take((size_t)N_NODES * D * 2);
    unsigned short* W1t    = (unsigned short*)take((size_t)R_AUG * D * D * 2);
    unsigned short* W2t    = (unsigned short*)take((size_t)R_AUG * D * D * 2);
    int*            cnt    = (int*)           take((size_t)N_NODES * 4);
    int*            offs   = (int*)           take((size_t)(N_NODES + 1) * 4);
    int*            cursor = (int*)           take((size_t)N_NODES * 4);
    uint2*          sorted = (uint2*)         take((size_t)E_AUG * 8);

    size_t zslice = (size_t)N_NODES * D * 2;
    size_t zavail = (ws_size > off) ? (ws_size - off) : 0;
    int Rc = (int)(zavail / zslice);
    if (Rc > R_AUG) Rc = R_AUG;
    if (Rc < 1) Rc = 1;
    unsigned short* Z = (unsigned short*)(base + off);

    hipMemsetAsync(norm, 0, (size_t)R_AUG * N_NODES * 4, stream);
    hipMemsetAsync(cnt, 0, (size_t)N_NODES * 4, stream);
    convert_x<<<dim3((N_NODES * D) / 256), 256, 0, stream>>>(emb, xb);
    init_h<<<dim3((N_NODES * D) / 256), 256, 0, stream>>>(h1, h2, b1, b2);
    transpose_w<<<dim3(2, 2, 2 * R_AUG), 256, 0, stream>>>(W1, W2, W1t, W2t);
    deg_hist<<<dim3((E_AUG + 255) / 256), 256, 0, stream>>>(graph, norm, cnt);
    inv_kernel<<<dim3((R_AUG * N_NODES + 255) / 256), 256, 0, stream>>>(norm);
    scan_kernel<<<dim3(1), 256, 0, stream>>>(cnt, offs, cursor);
    scatter_kernel<<<dim3((E_AUG + 255) / 256), 256, 0, stream>>>(graph, norm, cursor, sorted);

    const int nmt = (N_NODES + 127) / 128;  // 79
    for (int r0 = 0; r0 < R_AUG; r0 += Rc) {
        int rn = R_AUG - r0 < Rc ? R_AUG - r0 : Rc;
        gemm_chunk<<<dim3(nmt, rn), 256, 0, stream>>>(xb, W1t, Z, r0);
        agg_pass<<<dim3((N_NODES + 3) / 4), 256, 0, stream>>>(sorted, offs, Z, h1, r0, r0 + rn);
    }
    relu_conv<<<dim3((N_NODES * D) / 256), 256, 0, stream>>>(h1, h1b);
    for (int r0 = 0; r0 < R_AUG; r0 += Rc) {
        int rn = R_AUG - r0 < Rc ? R_AUG - r0 : Rc;
        gemm_chunk<<<dim3(nmt, rn), 256, 0, stream>>>(h1b, W2t, Z, r0);
        agg_pass<<<dim3((N_NODES + 3) / 4), 256, 0, stream>>>(sorted, offs, Z, h2, r0, r0 + rn);
    }
    score_kernel<<<dim3(N_BATCH / 4), 256, 0, stream>>>(batch, h2, rels, out);
}